// Round 1
// baseline (895.620 us; speedup 1.0000x reference)
//
#include <hip/hip_runtime.h>
#include <hip/hip_bf16.h>

#define N_NODES 100000
#define N_EDGES 3200000
#define DFEAT 256
#define UNITS 256

#define CHUNK 1024
#define NCHUNKS ((N_NODES + CHUNK - 1) / CHUNK)   // 98

typedef short bf16x8 __attribute__((ext_vector_type(8)));  // 8 bf16 (4 VGPRs), guide §3
typedef float f32x4 __attribute__((ext_vector_type(4)));

// RNE float -> bf16 bits
__device__ __forceinline__ unsigned short f2bf(float f) {
    union { float f; unsigned u; } v; v.f = f;
    unsigned u = v.u;
    u += 0x7FFFu + ((u >> 16) & 1u);
    return (unsigned short)(u >> 16);
}

// ---------------------------------------------------------------------------
// x (fp32, N x 256) -> xh (bf16). 1 float4 per thread.
// ---------------------------------------------------------------------------
__global__ __launch_bounds__(256) void convert_x(const float4* __restrict__ x4,
                                                 unsigned short* __restrict__ xh) {
    size_t i = (size_t)blockIdx.x * 256 + threadIdx.x;   // 6.4M float4s
    float4 v = x4[i];
    ushort4 o = make_ushort4(f2bf(v.x), f2bf(v.y), f2bf(v.z), f2bf(v.w));
    *(ushort4*)&xh[i * 4] = o;
}

// ---------------------------------------------------------------------------
// W (fp32, [k][n] 256x256) -> Wt (bf16, [n][k]) so GEMM B-fragments are
// contiguous along k in LDS. Tiny (65K elems).
// ---------------------------------------------------------------------------
__global__ void convert_w(const float* __restrict__ w, unsigned short* __restrict__ wt) {
    int n = blockIdx.x, k = threadIdx.x;
    wt[n * DFEAT + k] = f2bf(w[k * UNITS + n]);
}

// ---------------------------------------------------------------------------
// CSR build: histogram -> 2-level scan -> two-level binned scatter.
// ---------------------------------------------------------------------------
__global__ __launch_bounds__(256) void hist_rows(const int* __restrict__ erow,
                                                 int* __restrict__ cnt) {
    int e = blockIdx.x * 256 + threadIdx.x;
    if (e < N_EDGES) atomicAdd(&cnt[erow[e]], 1);
}

__global__ __launch_bounds__(256) void chunk_sums_k(const int* __restrict__ cnt,
                                                    int* __restrict__ csum) {
    __shared__ int red[256];
    int base = blockIdx.x * CHUNK;
    int s = 0;
    for (int i = threadIdx.x; i < CHUNK; i += 256) {
        int idx = base + i;
        s += (idx < N_NODES) ? cnt[idx] : 0;
    }
    red[threadIdx.x] = s;
    __syncthreads();
    for (int off = 128; off > 0; off >>= 1) {
        if (threadIdx.x < off) red[threadIdx.x] += red[threadIdx.x + off];
        __syncthreads();
    }
    if (threadIdx.x == 0) csum[blockIdx.x] = red[0];
}

// exclusive scan of chunk sums; also seeds the chunk-bin cursors (bcur).
__global__ void scan_chunk_sums(int* csum, int* bcur) {
    if (threadIdx.x == 0) {
        int run = 0;
        for (int i = 0; i < NCHUNKS; ++i) {
            int t = csum[i];
            csum[i] = run;
            bcur[i] = run;
            run += t;
        }
    }
}

__global__ __launch_bounds__(256) void scan_final(const int* __restrict__ cnt,
                                                  const int* __restrict__ csum,
                                                  int* __restrict__ row_ptr,
                                                  int* __restrict__ cursor) {
    __shared__ int tsum[256];
    const int tid = threadIdx.x;
    int base = blockIdx.x * CHUNK + tid * 4;
    int v[4];
#pragma unroll
    for (int j = 0; j < 4; ++j) {
        int idx = base + j;
        v[j] = (idx < N_NODES) ? cnt[idx] : 0;
    }
    int local = v[0] + v[1] + v[2] + v[3];
    tsum[tid] = local;
    __syncthreads();
    for (int off = 1; off < 256; off <<= 1) {
        int t = 0;
        if (tid >= off) t = tsum[tid - off];
        __syncthreads();
        if (tid >= off) tsum[tid] += t;
        __syncthreads();
    }
    int prefix = csum[blockIdx.x] + tsum[tid] - local;
#pragma unroll
    for (int j = 0; j < 4; ++j) {
        int idx = base + j;
        if (idx < N_NODES) { row_ptr[idx] = prefix; cursor[idx] = prefix; }
        prefix += v[j];
    }
}

// ---------------------------------------------------------------------------
// Pass 1: coarse scatter to CHUNK granularity. Each wg histograms its tile
// into LDS, reserves a contiguous run per chunk with ONE global atomic, then
// writes 8B records (packed col/val + row) into chunk-grouped `bin`.
// Writes are runs of ~21 consecutive records per (wg, chunk) -> full-line HBM
// writes instead of fill_csr's 15x-amplified random 4B scatter.
// ---------------------------------------------------------------------------
#define BIN_TILE 2048
#define BIN_NWG ((N_EDGES + BIN_TILE - 1) / BIN_TILE)   // 1563

__global__ __launch_bounds__(256) void bin_edges(const int* __restrict__ erow,
                                                 const int* __restrict__ ecol,
                                                 const float* __restrict__ eval,
                                                 int* __restrict__ bcur,
                                                 uint2* __restrict__ bin) {
    __shared__ int hist[NCHUNKS];
    __shared__ int sbase[NCHUNKS];
    __shared__ int scnt[NCHUNKS];
    const int tid = threadIdx.x;
    const int base = blockIdx.x * BIN_TILE;

    if (tid < NCHUNKS) hist[tid] = 0;
    __syncthreads();

    int r[8];
#pragma unroll
    for (int j = 0; j < 8; ++j) {
        int e = base + j * 256 + tid;
        r[j] = (e < N_EDGES) ? erow[e] : -1;
        if (r[j] >= 0) atomicAdd(&hist[r[j] >> 10], 1);   // CHUNK = 2^10
    }
    __syncthreads();

    if (tid < NCHUNKS) {
        sbase[tid] = atomicAdd(&bcur[tid], hist[tid]);    // contiguous run per chunk
        scnt[tid] = 0;
    }
    __syncthreads();

#pragma unroll
    for (int j = 0; j < 8; ++j) {
        int e = base + j * 256 + tid;
        if (r[j] >= 0) {
            int b = r[j] >> 10;
            int pos = sbase[b] + atomicAdd(&scnt[b], 1);
            unsigned packed = (((unsigned)ecol[e]) << 15) | (f2bf(eval[e]) & 0x7FFFu);
            bin[pos] = make_uint2(packed, (unsigned)r[j]);
        }
    }
}

// ---------------------------------------------------------------------------
// Pass 2: fine scatter within each chunk. Destination cv window per chunk is
// ~131 KB and the cursor window 4 KB -> both L2-resident while the chunk is
// processed, so the random placement never reaches HBM half-filled.
// ---------------------------------------------------------------------------
#define SLICES 8

__global__ __launch_bounds__(256) void scatter_fine(const int* __restrict__ csum,
                                                    const uint2* __restrict__ bin,
                                                    int* __restrict__ cursor,
                                                    unsigned* __restrict__ cv) {
    const int b = blockIdx.x;
    const int start = csum[b];
    const int end = (b + 1 < NCHUNKS) ? csum[b + 1] : N_EDGES;
    const int count = end - start;
    for (int i = blockIdx.y * 256 + threadIdx.x; i < count; i += SLICES * 256) {
        uint2 rec = bin[start + i];
        int pos = atomicAdd(&cursor[(int)rec.y], 1);
        cv[pos] = rec.x;
    }
}

// ---------------------------------------------------------------------------
// Aggregate: one wave per row, bf16 x gather (8 B/lane), fp32 accumulate,
// bf16 tmp write. Zero float atomics.
// ---------------------------------------------------------------------------
__global__ __launch_bounds__(256) void gather_rows(const int* __restrict__ row_ptr,
                                                   const int* __restrict__ cnt,
                                                   const unsigned* __restrict__ cv,
                                                   const unsigned short* __restrict__ xh,
                                                   unsigned short* __restrict__ tmp) {
    const int row = blockIdx.x * 4 + (threadIdx.x >> 6);
    if (row >= N_NODES) return;
    const int lane = threadIdx.x & 63;
    const int start = row_ptr[row];
    const int deg = cnt[row];
    const unsigned* __restrict__ p = cv + start;
    const uint2* __restrict__ x2 = (const uint2*)xh;   // row = 64 x uint2 (4 bf16 each)

    float a0 = 0.f, a1 = 0.f, a2 = 0.f, a3 = 0.f;
    int i = 0;
    for (; i + 1 < deg; i += 2) {
        unsigned e0 = p[i], e1 = p[i + 1];
        uint2 g0 = x2[(size_t)(e0 >> 15) * 64 + lane];
        uint2 g1 = x2[(size_t)(e1 >> 15) * 64 + lane];
        float v0 = __uint_as_float((e0 & 0x7FFFu) << 16);
        float v1 = __uint_as_float((e1 & 0x7FFFu) << 16);
        a0 = fmaf(v0, __uint_as_float(g0.x << 16), a0);
        a1 = fmaf(v0, __uint_as_float(g0.x & 0xFFFF0000u), a1);
        a2 = fmaf(v0, __uint_as_float(g0.y << 16), a2);
        a3 = fmaf(v0, __uint_as_float(g0.y & 0xFFFF0000u), a3);
        a0 = fmaf(v1, __uint_as_float(g1.x << 16), a0);
        a1 = fmaf(v1, __uint_as_float(g1.x & 0xFFFF0000u), a1);
        a2 = fmaf(v1, __uint_as_float(g1.y << 16), a2);
        a3 = fmaf(v1, __uint_as_float(g1.y & 0xFFFF0000u), a3);
    }
    if (i < deg) {
        unsigned e0 = p[i];
        uint2 g0 = x2[(size_t)(e0 >> 15) * 64 + lane];
        float v0 = __uint_as_float((e0 & 0x7FFFu) << 16);
        a0 = fmaf(v0, __uint_as_float(g0.x << 16), a0);
        a1 = fmaf(v0, __uint_as_float(g0.x & 0xFFFF0000u), a1);
        a2 = fmaf(v0, __uint_as_float(g0.y << 16), a2);
        a3 = fmaf(v0, __uint_as_float(g0.y & 0xFFFF0000u), a3);
    }
    ushort4 o = make_ushort4(f2bf(a0), f2bf(a1), f2bf(a2), f2bf(a3));
    *(ushort4*)&tmp[(size_t)row * 256 + lane * 4] = o;
}

// ---------------------------------------------------------------------------
// out = relu(tmp @ W + bias) via bf16 MFMA 16x16x32.
// 128x128 block, 4 waves (2m x 2n), each wave 64x64 = 4x4 tiles of 16x16.
// As/Bs rows padded to 72 bf16 (16B pad) -> frag reads are 2-way max (free).
// Fragment layout (m89-verified): A m=lane&15, k=quad*8+j; C/D col=lane&15,
// row=quad*4+reg.
// ---------------------------------------------------------------------------
#define GBM 128
#define GBN 128
#define GBK 64
#define LDK 72

__global__ __launch_bounds__(256) void gemm_mfma(
    const unsigned short* __restrict__ A,    // tmp bf16 [M][256]
    const unsigned short* __restrict__ Bt,   // Wt bf16 [N][K] = [256][256]
    const float* __restrict__ bias,
    float* __restrict__ C, int M)
{
    __shared__ unsigned short As[GBM * LDK];
    __shared__ unsigned short Bs[GBN * LDK];

    const int tid = threadIdx.x;
    const int lane = tid & 63;
    const int wid = tid >> 6;
    const int wave_m = wid & 1, wave_n = wid >> 1;
    const int block_m = blockIdx.x * GBM;
    const int block_n = blockIdx.y * GBN;

    const int r = tid >> 1;        // staging row 0..127
    const int half = tid & 1;      // which 32-elem half of the 64-wide k-chunk

    const int quad = lane >> 4;
    const int l16 = lane & 15;

    f32x4 acc[4][4];
#pragma unroll
    for (int i = 0; i < 4; ++i)
#pragma unroll
        for (int j = 0; j < 4; ++j)
            acc[i][j] = {0.f, 0.f, 0.f, 0.f};

    for (int k0 = 0; k0 < DFEAT; k0 += GBK) {
        // --- stage A tile (guarded) ---
        {
            const int gm = block_m + r;
            uint4 v[4] = {};
            if (gm < M) {
                const uint4* src = (const uint4*)(A + (size_t)gm * DFEAT + k0 + half * 32);
                v[0] = src[0]; v[1] = src[1]; v[2] = src[2]; v[3] = src[3];
            }
            uint4* dst = (uint4*)&As[r * LDK + half * 32];
            dst[0] = v[0]; dst[1] = v[1]; dst[2] = v[2]; dst[3] = v[3];
        }
        // --- stage B tile (N=256 exact, no guard) ---
        {
            const uint4* src = (const uint4*)(Bt + (size_t)(block_n + r) * DFEAT + k0 + half * 32);
            uint4* dst = (uint4*)&Bs[r * LDK + half * 32];
            dst[0] = src[0]; dst[1] = src[1]; dst[2] = src[2]; dst[3] = src[3];
        }
        __syncthreads();

#pragma unroll
        for (int kc = 0; kc < 2; ++kc) {
            const int ko = kc * 32 + quad * 8;
            bf16x8 af[4], bfr[4];
#pragma unroll
            for (int i = 0; i < 4; ++i)
                af[i] = *(const bf16x8*)&As[(wave_m * 64 + i * 16 + l16) * LDK + ko];
#pragma unroll
            for (int j = 0; j < 4; ++j)
                bfr[j] = *(const bf16x8*)&Bs[(wave_n * 64 + j * 16 + l16) * LDK + ko];
#pragma unroll
            for (int i = 0; i < 4; ++i)
#pragma unroll
                for (int j = 0; j < 4; ++j)
                    acc[i][j] = __builtin_amdgcn_mfma_f32_16x16x32_bf16(
                        af[i], bfr[j], acc[i][j], 0, 0, 0);
        }
        __syncthreads();
    }

    // epilogue: bias + relu
#pragma unroll
    for (int j = 0; j < 4; ++j) {
        const int n = block_n + wave_n * 64 + j * 16 + l16;
        const float bj = bias[n];
#pragma unroll
        for (int i = 0; i < 4; ++i) {
            const int m0 = block_m + wave_m * 64 + i * 16 + quad * 4;
#pragma unroll
            for (int rg = 0; rg < 4; ++rg) {
                const int m = m0 + rg;
                if (m < M)
                    C[(size_t)m * UNITS + n] = fmaxf(acc[i][j][rg] + bj, 0.f);
            }
        }
    }
}

extern "C" void kernel_launch(void* const* d_in, const int* in_sizes, int n_in,
                              void* d_out, int out_size, void* d_ws, size_t ws_size,
                              hipStream_t stream) {
    const int*   erow = (const int*)d_in[0];
    const int*   ecol = (const int*)d_in[1];
    const float* eval = (const float*)d_in[2];
    const float* x    = (const float*)d_in[3];
    const float* w    = (const float*)d_in[4];
    const float* bias = (const float*)d_in[5];
    float* out = (float*)d_out;

    // Workspace carve-up (bytes, all 16B-aligned):
    //   tmp bf16  : 100000*256*2 = 51,200,000
    //   row_ptr   : 400,000
    //   cnt       : 400,000
    //   cursor    : 400,000
    //   csum      : 4,096
    //   cv (u32)  : 12,800,000
    //   Wt bf16   : 262,144
    //   bin (u64) : 25,600,000
    //   bcur      : 4,096          total ~91.1 MB (R2 proved ws >= 129 MB)
    char* ws = (char*)d_ws;
    unsigned short* tmp     = (unsigned short*)(ws);
    int*            row_ptr = (int*)(ws + 51200000);
    int*            cnt     = (int*)(ws + 51600000);
    int*            cursor  = (int*)(ws + 52000000);
    int*            csum    = (int*)(ws + 52400000);
    unsigned*       cv      = (unsigned*)(ws + 52404096);
    unsigned short* wt      = (unsigned short*)(ws + 65204096);
    uint2*          bin     = (uint2*)(ws + 65466240);
    int*            bcur    = (int*)(ws + 91066240);

    // xh (bf16 x, 51.2 MB) lives in d_out's buffer — dead before gemm writes out.
    unsigned short* xh = (unsigned short*)d_out;

    // dtype converts (independent of CSR build)
    convert_x<<<(N_NODES * DFEAT / 4) / 256, 256, 0, stream>>>((const float4*)x, xh);
    convert_w<<<UNITS, DFEAT, 0, stream>>>(w, wt);

    // CSR build (int atomics only)
    hipMemsetAsync(cnt, 0, N_NODES * sizeof(int), stream);
    hist_rows<<<(N_EDGES + 255) / 256, 256, 0, stream>>>(erow, cnt);
    chunk_sums_k<<<NCHUNKS, 256, 0, stream>>>(cnt, csum);
    scan_chunk_sums<<<1, 64, 0, stream>>>(csum, bcur);
    scan_final<<<NCHUNKS, 256, 0, stream>>>(cnt, csum, row_ptr, cursor);

    // two-level binned scatter (replaces fill_csr's 15x-amplified random write)
    bin_edges<<<BIN_NWG, 256, 0, stream>>>(erow, ecol, eval, bcur, bin);
    scatter_fine<<<dim3(NCHUNKS, SLICES), 256, 0, stream>>>(csum, bin, cursor, cv);

    // tmp = A_coo @ X (bf16 in / fp32 acc / bf16 out)
    gather_rows<<<(N_NODES + 3) / 4, 256, 0, stream>>>(row_ptr, cnt, cv, xh, tmp);

    // out = relu(tmp @ W + bias) via bf16 MFMA
    dim3 grid((N_NODES + GBM - 1) / GBM, UNITS / GBN);
    gemm_mfma<<<grid, 256, 0, stream>>>(tmp, wt, bias, out, N_NODES);
}

// Round 2
// 702.829 us; speedup vs baseline: 1.2743x; 1.2743x over previous
//
#include <hip/hip_runtime.h>
#include <hip/hip_bf16.h>

#define N_NODES 100000
#define N_EDGES 3200000
#define DFEAT 256
#define UNITS 256

#define CHUNK 512
#define CHUNK_SHIFT 9
#define NCHUNKS ((N_NODES + CHUNK - 1) / CHUNK)   // 196

typedef short bf16x8 __attribute__((ext_vector_type(8)));  // 8 bf16 (4 VGPRs), guide §3
typedef float f32x4 __attribute__((ext_vector_type(4)));

// RNE float -> bf16 bits
__device__ __forceinline__ unsigned short f2bf(float f) {
    union { float f; unsigned u; } v; v.f = f;
    unsigned u = v.u;
    u += 0x7FFFu + ((u >> 16) & 1u);
    return (unsigned short)(u >> 16);
}

// ---------------------------------------------------------------------------
// x (fp32, N x 256) -> xh (bf16). 1 float4 per thread.
// ---------------------------------------------------------------------------
__global__ __launch_bounds__(256) void convert_x(const float4* __restrict__ x4,
                                                 unsigned short* __restrict__ xh) {
    size_t i = (size_t)blockIdx.x * 256 + threadIdx.x;   // 6.4M float4s
    float4 v = x4[i];
    ushort4 o = make_ushort4(f2bf(v.x), f2bf(v.y), f2bf(v.z), f2bf(v.w));
    *(ushort4*)&xh[i * 4] = o;
}

// ---------------------------------------------------------------------------
// W (fp32, [k][n] 256x256) -> Wt (bf16, [n][k]) so GEMM B-fragments are
// contiguous along k in LDS. Tiny (65K elems).
// ---------------------------------------------------------------------------
__global__ void convert_w(const float* __restrict__ w, unsigned short* __restrict__ wt) {
    int n = blockIdx.x, k = threadIdx.x;
    wt[n * DFEAT + k] = f2bf(w[k * UNITS + n]);
}

// ---------------------------------------------------------------------------
// CSR build: histogram -> 2-level scan -> LDS-sorted binning -> per-chunk
// LDS-cursor counting sort. Zero global atomic-returns on the hot path.
// ---------------------------------------------------------------------------
__global__ __launch_bounds__(256) void hist_rows(const int* __restrict__ erow,
                                                 int* __restrict__ cnt) {
    int e = blockIdx.x * 256 + threadIdx.x;
    if (e < N_EDGES) atomicAdd(&cnt[erow[e]], 1);
}

__global__ __launch_bounds__(256) void chunk_sums_k(const int* __restrict__ cnt,
                                                    int* __restrict__ csum) {
    __shared__ int red[256];
    int base = blockIdx.x * CHUNK;
    int s = 0;
    for (int i = threadIdx.x; i < CHUNK; i += 256) {
        int idx = base + i;
        s += (idx < N_NODES) ? cnt[idx] : 0;
    }
    red[threadIdx.x] = s;
    __syncthreads();
    for (int off = 128; off > 0; off >>= 1) {
        if (threadIdx.x < off) red[threadIdx.x] += red[threadIdx.x + off];
        __syncthreads();
    }
    if (threadIdx.x == 0) csum[blockIdx.x] = red[0];
}

// Parallel exclusive scan of the 196 chunk sums (replaces the serial
// 196-step dependent-load chain); seeds bcur with the same bases.
__global__ __launch_bounds__(256) void scan_chunks(int* csum, int* bcur) {
    __shared__ int t[256];
    const int tid = threadIdx.x;
    int v = (tid < NCHUNKS) ? csum[tid] : 0;
    t[tid] = v;
    __syncthreads();
    for (int off = 1; off < 256; off <<= 1) {
        int u = 0;
        if (tid >= off) u = t[tid - off];
        __syncthreads();
        if (tid >= off) t[tid] += u;
        __syncthreads();
    }
    int excl = t[tid] - v;
    if (tid < NCHUNKS) { csum[tid] = excl; bcur[tid] = excl; }
}

__global__ __launch_bounds__(256) void scan_final(const int* __restrict__ cnt,
                                                  const int* __restrict__ csum,
                                                  int* __restrict__ row_ptr) {
    __shared__ int tsum[256];
    const int tid = threadIdx.x;
    const int base = blockIdx.x * CHUNK + tid * 2;
    int v0 = (base < N_NODES) ? cnt[base] : 0;
    int v1 = (base + 1 < N_NODES) ? cnt[base + 1] : 0;
    int local = v0 + v1;
    tsum[tid] = local;
    __syncthreads();
    for (int off = 1; off < 256; off <<= 1) {
        int u = 0;
        if (tid >= off) u = tsum[tid - off];
        __syncthreads();
        if (tid >= off) tsum[tid] += u;
        __syncthreads();
    }
    int prefix = csum[blockIdx.x] + tsum[tid] - local;
    if (base < N_NODES) row_ptr[base] = prefix;
    if (base + 1 < N_NODES) row_ptr[base + 1] = prefix + v0;
}

// ---------------------------------------------------------------------------
// Pass 1: per-wg LDS counting sort by chunk, then COALESCED run writes.
// Each wg: (1) LDS histogram of its 2048 edges over 196 chunks, (2) LDS scan,
// (3) one global atomic per chunk reserves a contiguous run in `bin`,
// (4) LDS scatter into a chunk-sorted 16KB record buffer, (5) linear sweep
// writes the sorted block out — consecutive lanes hit consecutive addresses
// within each ~10-record run (burst writes, not the random 8B scatter that
// cost 15x amplification before).
// ---------------------------------------------------------------------------
#define BIN_TILE 2048
#define BIN_NWG ((N_EDGES + BIN_TILE - 1) / BIN_TILE)   // 1563

__global__ __launch_bounds__(256) void bin_edges(const int* __restrict__ erow,
                                                 const int* __restrict__ ecol,
                                                 const float* __restrict__ eval,
                                                 int* __restrict__ bcur,
                                                 uint2* __restrict__ bin) {
    __shared__ int hist[256];    // hist -> inclusive scan (excl[b] = hist[b-1])
    __shared__ int scnt[256];
    __shared__ int delta[256];   // sbase[b] - excl[b]
    __shared__ uint2 rec[BIN_TILE];
    const int tid = threadIdx.x;
    const int base = blockIdx.x * BIN_TILE;

    hist[tid] = 0;
    __syncthreads();

    int r[8]; unsigned pk[8];
#pragma unroll
    for (int j = 0; j < 8; ++j) {
        int e = base + j * 256 + tid;
        if (e < N_EDGES) {
            r[j] = erow[e];
            pk[j] = (((unsigned)ecol[e]) << 15) | (f2bf(eval[e]) & 0x7FFFu);
            atomicAdd(&hist[r[j] >> CHUNK_SHIFT], 1);
        } else {
            r[j] = -1;
        }
    }
    __syncthreads();

    const int cntb = hist[tid];
    // inclusive Hillis-Steele scan of hist in place
    for (int off = 1; off < 256; off <<= 1) {
        int u = 0;
        if (tid >= off) u = hist[tid - off];
        __syncthreads();
        if (tid >= off) hist[tid] += u;
        __syncthreads();
    }
    const int excl = hist[tid] - cntb;
    if (tid < NCHUNKS) delta[tid] = atomicAdd(&bcur[tid], cntb) - excl;
    scnt[tid] = 0;
    __syncthreads();

    // LDS scatter into chunk-sorted order
#pragma unroll
    for (int j = 0; j < 8; ++j) {
        if (r[j] >= 0) {
            int b = r[j] >> CHUNK_SHIFT;
            int s = (b ? hist[b - 1] : 0) + atomicAdd(&scnt[b], 1);
            rec[s] = make_uint2(pk[j], (unsigned)r[j]);
        }
    }
    __syncthreads();

    // linear, mostly-coalesced write-out: global pos = delta[b] + s
    const int n = min(BIN_TILE, N_EDGES - base);
    for (int s = tid; s < n; s += 256) {
        uint2 q = rec[s];
        bin[delta[(int)q.y >> CHUNK_SHIFT] + s] = q;
    }
}

// ---------------------------------------------------------------------------
// Pass 2: per-chunk counting sort with LDS cursors (init from row_ptr).
// One wg per chunk; reads its bin span sequentially, writes cv within an
// L2-hot 65KB window. ZERO global atomics.
// ---------------------------------------------------------------------------
__global__ __launch_bounds__(512) void sort_chunk(const int* __restrict__ csum,
                                                  const int* __restrict__ row_ptr,
                                                  const uint2* __restrict__ bin,
                                                  unsigned* __restrict__ cv) {
    __shared__ int cur[CHUNK];
    const int b = blockIdx.x;
    const int rbase = b << CHUNK_SHIFT;
    const int start = csum[b];
    const int end = (b + 1 < NCHUNKS) ? csum[b + 1] : N_EDGES;
    const int tid = threadIdx.x;

    if (tid < CHUNK) {
        int row = rbase + tid;
        cur[tid] = (row < N_NODES) ? row_ptr[row] : 0;
    }
    __syncthreads();

    int i = start + tid;
    for (; i + 3 * 512 < end; i += 4 * 512) {
        uint2 q0 = bin[i], q1 = bin[i + 512], q2 = bin[i + 1024], q3 = bin[i + 1536];
        int p0 = atomicAdd(&cur[q0.y & (CHUNK - 1)], 1);
        int p1 = atomicAdd(&cur[q1.y & (CHUNK - 1)], 1);
        int p2 = atomicAdd(&cur[q2.y & (CHUNK - 1)], 1);
        int p3 = atomicAdd(&cur[q3.y & (CHUNK - 1)], 1);
        cv[p0] = q0.x; cv[p1] = q1.x; cv[p2] = q2.x; cv[p3] = q3.x;
    }
    for (; i < end; i += 512) {
        uint2 q = bin[i];
        int p = atomicAdd(&cur[q.y & (CHUNK - 1)], 1);
        cv[p] = q.x;
    }
}

// ---------------------------------------------------------------------------
// Aggregate: one wave per row, bf16 x gather (8 B/lane), fp32 accumulate,
// bf16 tmp write. Unroll-4 edge loop -> 4 independent 512B row gathers in
// flight per wave (was 2): kernel is latency/MLP-bound, not BW-bound.
// ---------------------------------------------------------------------------
__global__ __launch_bounds__(256) void gather_rows(const int* __restrict__ row_ptr,
                                                   const int* __restrict__ cnt,
                                                   const unsigned* __restrict__ cv,
                                                   const unsigned short* __restrict__ xh,
                                                   unsigned short* __restrict__ tmp) {
    const int row = blockIdx.x * 4 + (threadIdx.x >> 6);
    if (row >= N_NODES) return;
    const int lane = threadIdx.x & 63;
    const int start = row_ptr[row];
    const int deg = cnt[row];
    const unsigned* __restrict__ p = cv + start;
    const uint2* __restrict__ x2 = (const uint2*)xh;   // row = 64 x uint2 (4 bf16 each)

    float a0 = 0.f, a1 = 0.f, a2 = 0.f, a3 = 0.f;
    int i = 0;
    for (; i + 3 < deg; i += 4) {
        unsigned e0 = p[i], e1 = p[i + 1], e2 = p[i + 2], e3 = p[i + 3];
        uint2 g0 = x2[(size_t)(e0 >> 15) * 64 + lane];
        uint2 g1 = x2[(size_t)(e1 >> 15) * 64 + lane];
        uint2 g2 = x2[(size_t)(e2 >> 15) * 64 + lane];
        uint2 g3 = x2[(size_t)(e3 >> 15) * 64 + lane];
        float v0 = __uint_as_float((e0 & 0x7FFFu) << 16);
        float v1 = __uint_as_float((e1 & 0x7FFFu) << 16);
        float v2 = __uint_as_float((e2 & 0x7FFFu) << 16);
        float v3 = __uint_as_float((e3 & 0x7FFFu) << 16);
        a0 = fmaf(v0, __uint_as_float(g0.x << 16), a0);
        a1 = fmaf(v0, __uint_as_float(g0.x & 0xFFFF0000u), a1);
        a2 = fmaf(v0, __uint_as_float(g0.y << 16), a2);
        a3 = fmaf(v0, __uint_as_float(g0.y & 0xFFFF0000u), a3);
        a0 = fmaf(v1, __uint_as_float(g1.x << 16), a0);
        a1 = fmaf(v1, __uint_as_float(g1.x & 0xFFFF0000u), a1);
        a2 = fmaf(v1, __uint_as_float(g1.y << 16), a2);
        a3 = fmaf(v1, __uint_as_float(g1.y & 0xFFFF0000u), a3);
        a0 = fmaf(v2, __uint_as_float(g2.x << 16), a0);
        a1 = fmaf(v2, __uint_as_float(g2.x & 0xFFFF0000u), a1);
        a2 = fmaf(v2, __uint_as_float(g2.y << 16), a2);
        a3 = fmaf(v2, __uint_as_float(g2.y & 0xFFFF0000u), a3);
        a0 = fmaf(v3, __uint_as_float(g3.x << 16), a0);
        a1 = fmaf(v3, __uint_as_float(g3.x & 0xFFFF0000u), a1);
        a2 = fmaf(v3, __uint_as_float(g3.y << 16), a2);
        a3 = fmaf(v3, __uint_as_float(g3.y & 0xFFFF0000u), a3);
    }
    for (; i + 1 < deg; i += 2) {
        unsigned e0 = p[i], e1 = p[i + 1];
        uint2 g0 = x2[(size_t)(e0 >> 15) * 64 + lane];
        uint2 g1 = x2[(size_t)(e1 >> 15) * 64 + lane];
        float v0 = __uint_as_float((e0 & 0x7FFFu) << 16);
        float v1 = __uint_as_float((e1 & 0x7FFFu) << 16);
        a0 = fmaf(v0, __uint_as_float(g0.x << 16), a0);
        a1 = fmaf(v0, __uint_as_float(g0.x & 0xFFFF0000u), a1);
        a2 = fmaf(v0, __uint_as_float(g0.y << 16), a2);
        a3 = fmaf(v0, __uint_as_float(g0.y & 0xFFFF0000u), a3);
        a0 = fmaf(v1, __uint_as_float(g1.x << 16), a0);
        a1 = fmaf(v1, __uint_as_float(g1.x & 0xFFFF0000u), a1);
        a2 = fmaf(v1, __uint_as_float(g1.y << 16), a2);
        a3 = fmaf(v1, __uint_as_float(g1.y & 0xFFFF0000u), a3);
    }
    if (i < deg) {
        unsigned e0 = p[i];
        uint2 g0 = x2[(size_t)(e0 >> 15) * 64 + lane];
        float v0 = __uint_as_float((e0 & 0x7FFFu) << 16);
        a0 = fmaf(v0, __uint_as_float(g0.x << 16), a0);
        a1 = fmaf(v0, __uint_as_float(g0.x & 0xFFFF0000u), a1);
        a2 = fmaf(v0, __uint_as_float(g0.y << 16), a2);
        a3 = fmaf(v0, __uint_as_float(g0.y & 0xFFFF0000u), a3);
    }
    ushort4 o = make_ushort4(f2bf(a0), f2bf(a1), f2bf(a2), f2bf(a3));
    *(ushort4*)&tmp[(size_t)row * 256 + lane * 4] = o;
}

// ---------------------------------------------------------------------------
// out = relu(tmp @ W + bias) via bf16 MFMA 16x16x32.
// 128x128 block, 4 waves (2m x 2n), each wave 64x64 = 4x4 tiles of 16x16.
// As/Bs rows padded to 72 bf16 (16B pad) -> frag reads are 2-way max (free).
// Fragment layout (m89-verified): A m=lane&15, k=quad*8+j; C/D col=lane&15,
// row=quad*4+reg.
// ---------------------------------------------------------------------------
#define GBM 128
#define GBN 128
#define GBK 64
#define LDK 72

__global__ __launch_bounds__(256) void gemm_mfma(
    const unsigned short* __restrict__ A,    // tmp bf16 [M][256]
    const unsigned short* __restrict__ Bt,   // Wt bf16 [N][K] = [256][256]
    const float* __restrict__ bias,
    float* __restrict__ C, int M)
{
    __shared__ unsigned short As[GBM * LDK];
    __shared__ unsigned short Bs[GBN * LDK];

    const int tid = threadIdx.x;
    const int lane = tid & 63;
    const int wid = tid >> 6;
    const int wave_m = wid & 1, wave_n = wid >> 1;
    const int block_m = blockIdx.x * GBM;
    const int block_n = blockIdx.y * GBN;

    const int r = tid >> 1;        // staging row 0..127
    const int half = tid & 1;      // which 32-elem half of the 64-wide k-chunk

    const int quad = lane >> 4;
    const int l16 = lane & 15;

    f32x4 acc[4][4];
#pragma unroll
    for (int i = 0; i < 4; ++i)
#pragma unroll
        for (int j = 0; j < 4; ++j)
            acc[i][j] = {0.f, 0.f, 0.f, 0.f};

    for (int k0 = 0; k0 < DFEAT; k0 += GBK) {
        // --- stage A tile (guarded) ---
        {
            const int gm = block_m + r;
            uint4 v[4] = {};
            if (gm < M) {
                const uint4* src = (const uint4*)(A + (size_t)gm * DFEAT + k0 + half * 32);
                v[0] = src[0]; v[1] = src[1]; v[2] = src[2]; v[3] = src[3];
            }
            uint4* dst = (uint4*)&As[r * LDK + half * 32];
            dst[0] = v[0]; dst[1] = v[1]; dst[2] = v[2]; dst[3] = v[3];
        }
        // --- stage B tile (N=256 exact, no guard) ---
        {
            const uint4* src = (const uint4*)(Bt + (size_t)(block_n + r) * DFEAT + k0 + half * 32);
            uint4* dst = (uint4*)&Bs[r * LDK + half * 32];
            dst[0] = src[0]; dst[1] = src[1]; dst[2] = src[2]; dst[3] = src[3];
        }
        __syncthreads();

#pragma unroll
        for (int kc = 0; kc < 2; ++kc) {
            const int ko = kc * 32 + quad * 8;
            bf16x8 af[4], bfr[4];
#pragma unroll
            for (int i = 0; i < 4; ++i)
                af[i] = *(const bf16x8*)&As[(wave_m * 64 + i * 16 + l16) * LDK + ko];
#pragma unroll
            for (int j = 0; j < 4; ++j)
                bfr[j] = *(const bf16x8*)&Bs[(wave_n * 64 + j * 16 + l16) * LDK + ko];
#pragma unroll
            for (int i = 0; i < 4; ++i)
#pragma unroll
                for (int j = 0; j < 4; ++j)
                    acc[i][j] = __builtin_amdgcn_mfma_f32_16x16x32_bf16(
                        af[i], bfr[j], acc[i][j], 0, 0, 0);
        }
        __syncthreads();
    }

    // epilogue: bias + relu
#pragma unroll
    for (int j = 0; j < 4; ++j) {
        const int n = block_n + wave_n * 64 + j * 16 + l16;
        const float bj = bias[n];
#pragma unroll
        for (int i = 0; i < 4; ++i) {
            const int m0 = block_m + wave_m * 64 + i * 16 + quad * 4;
#pragma unroll
            for (int rg = 0; rg < 4; ++rg) {
                const int m = m0 + rg;
                if (m < M)
                    C[(size_t)m * UNITS + n] = fmaxf(acc[i][j][rg] + bj, 0.f);
            }
        }
    }
}

extern "C" void kernel_launch(void* const* d_in, const int* in_sizes, int n_in,
                              void* d_out, int out_size, void* d_ws, size_t ws_size,
                              hipStream_t stream) {
    const int*   erow = (const int*)d_in[0];
    const int*   ecol = (const int*)d_in[1];
    const float* eval = (const float*)d_in[2];
    const float* x    = (const float*)d_in[3];
    const float* w    = (const float*)d_in[4];
    const float* bias = (const float*)d_in[5];
    float* out = (float*)d_out;

    // Workspace carve-up (bytes, all 16B-aligned):
    //   tmp bf16  : 100000*256*2 = 51,200,000
    //   row_ptr   : 400,000
    //   cnt       : 400,000
    //   (spare)   : 400,000
    //   csum      : 4,096
    //   cv (u32)  : 12,800,000
    //   Wt bf16   : 262,144
    //   bin (u64) : 25,600,000
    //   bcur      : 4,096          total ~91.1 MB (ws >= 129 MB proven)
    char* ws = (char*)d_ws;
    unsigned short* tmp     = (unsigned short*)(ws);
    int*            row_ptr = (int*)(ws + 51200000);
    int*            cnt     = (int*)(ws + 51600000);
    int*            csum    = (int*)(ws + 52400000);
    unsigned*       cv      = (unsigned*)(ws + 52404096);
    unsigned short* wt      = (unsigned short*)(ws + 65204096);
    uint2*          bin     = (uint2*)(ws + 65466240);
    int*            bcur    = (int*)(ws + 91066240);

    // xh (bf16 x, 51.2 MB) lives in d_out's buffer — dead before gemm writes out.
    unsigned short* xh = (unsigned short*)d_out;

    // dtype converts (independent of CSR build)
    convert_x<<<(N_NODES * DFEAT / 4) / 256, 256, 0, stream>>>((const float4*)x, xh);
    convert_w<<<UNITS, DFEAT, 0, stream>>>(w, wt);

    // CSR build
    hipMemsetAsync(cnt, 0, N_NODES * sizeof(int), stream);
    hist_rows<<<(N_EDGES + 255) / 256, 256, 0, stream>>>(erow, cnt);
    chunk_sums_k<<<NCHUNKS, 256, 0, stream>>>(cnt, csum);
    scan_chunks<<<1, 256, 0, stream>>>(csum, bcur);
    scan_final<<<NCHUNKS, 256, 0, stream>>>(cnt, csum, row_ptr);

    // LDS-sorted binning + per-chunk LDS-cursor counting sort
    bin_edges<<<BIN_NWG, 256, 0, stream>>>(erow, ecol, eval, bcur, bin);
    sort_chunk<<<NCHUNKS, 512, 0, stream>>>(csum, row_ptr, bin, cv);

    // tmp = A_coo @ X (bf16 in / fp32 acc / bf16 out)
    gather_rows<<<(N_NODES + 3) / 4, 256, 0, stream>>>(row_ptr, cnt, cv, xh, tmp);

    // out = relu(tmp @ W + bias) via bf16 MFMA
    dim3 grid((N_NODES + GBM - 1) / GBM, UNITS / GBN);
    gemm_mfma<<<grid, 256, 0, stream>>>(tmp, wt, bias, out, N_NODES);
}

// Round 3
// 537.675 us; speedup vs baseline: 1.6657x; 1.3072x over previous
//
#include <hip/hip_runtime.h>
#include <hip/hip_bf16.h>

#define N_NODES 100000
#define N_EDGES 3200000
#define DFEAT 256
#define UNITS 256

#define CHUNK 512
#define CHUNK_SHIFT 9
#define NCHUNKS ((N_NODES + CHUNK - 1) / CHUNK)   // 196

#define BIN_TILE 2048
#define BIN_NWG ((N_EDGES + BIN_TILE - 1) / BIN_TILE)   // 1563
#define PADC 208                                  // padded chunk stride in hist_all

typedef short bf16x8 __attribute__((ext_vector_type(8)));  // 8 bf16 (4 VGPRs), guide §3
typedef float f32x4 __attribute__((ext_vector_type(4)));

// RNE float -> bf16 bits
__device__ __forceinline__ unsigned short f2bf(float f) {
    union { float f; unsigned u; } v; v.f = f;
    unsigned u = v.u;
    u += 0x7FFFu + ((u >> 16) & 1u);
    return (unsigned short)(u >> 16);
}

// ---------------------------------------------------------------------------
// x (fp32, N x 256) -> xh (bf16). 1 float4 per thread.
// ---------------------------------------------------------------------------
__global__ __launch_bounds__(256) void convert_x(const float4* __restrict__ x4,
                                                 unsigned short* __restrict__ xh) {
    size_t i = (size_t)blockIdx.x * 256 + threadIdx.x;   // 6.4M float4s
    float4 v = x4[i];
    ushort4 o = make_ushort4(f2bf(v.x), f2bf(v.y), f2bf(v.z), f2bf(v.w));
    *(ushort4*)&xh[i * 4] = o;
}

// W (fp32, [k][n]) -> Wt (bf16, [n][k])
__global__ void convert_w(const float* __restrict__ w, unsigned short* __restrict__ wt) {
    int n = blockIdx.x, k = threadIdx.x;
    wt[n * DFEAT + k] = f2bf(w[k * UNITS + n]);
}

// ---------------------------------------------------------------------------
// CSR build, ZERO global atomics anywhere:
//   chunk_hist: per-wg LDS histogram over 196 chunks -> hist_all[wg][chunk]
//   col_scan:   per-chunk scan over the 1563 wgs -> deterministic run bases
//               (in place) + chunk totals
//   scan_chunks: exclusive scan of 196 totals -> csum
//   bin_edges:  LDS counting sort by chunk, coalesced run writes at the
//               precomputed base (no reservation atomic)
//   sort_chunk: per-chunk LDS row-histogram + scan -> row_ptr, then
//               LDS-cursor scatter of cv (bin span is L2-hot)
// This replaces hist_rows (3.2M cross-XCD atomic RMWs), chunk_sums_k,
// scan_final and the cnt memset.
// ---------------------------------------------------------------------------
__global__ __launch_bounds__(256) void chunk_hist(const int* __restrict__ erow,
                                                  int* __restrict__ hist_all) {
    __shared__ int h[256];
    const int tid = threadIdx.x;
    h[tid] = 0;
    __syncthreads();
    const int base = blockIdx.x * BIN_TILE;
#pragma unroll
    for (int j = 0; j < 8; ++j) {
        int e = base + j * 256 + tid;
        if (e < N_EDGES) atomicAdd(&h[erow[e] >> CHUNK_SHIFT], 1);
    }
    __syncthreads();
    if (tid < NCHUNKS) hist_all[blockIdx.x * PADC + tid] = h[tid];
}

// One block per chunk b: exclusive-scan hist_all[*][b] over wgs (in place),
// emit chunk total.
__global__ __launch_bounds__(256) void col_scan(int* __restrict__ hist_all,
                                                int* __restrict__ chunk_cnt) {
    __shared__ int t[256];
    const int b = blockIdx.x;
    const int tid = threadIdx.x;
    int v[7]; int local = 0;
#pragma unroll
    for (int j = 0; j < 7; ++j) {
        int w = tid * 7 + j;
        v[j] = (w < BIN_NWG) ? hist_all[w * PADC + b] : 0;
        local += v[j];
    }
    t[tid] = local;
    __syncthreads();
    for (int off = 1; off < 256; off <<= 1) {
        int u = 0;
        if (tid >= off) u = t[tid - off];
        __syncthreads();
        if (tid >= off) t[tid] += u;
        __syncthreads();
    }
    int run = t[tid] - local;   // exclusive prefix of this thread's span
#pragma unroll
    for (int j = 0; j < 7; ++j) {
        int w = tid * 7 + j;
        if (w < BIN_NWG) { hist_all[w * PADC + b] = run; run += v[j]; }
    }
    if (tid == 255) chunk_cnt[b] = t[255];
}

__global__ void scan_chunks(const int* __restrict__ chunk_cnt, int* __restrict__ csum) {
    __shared__ int t[256];
    const int tid = threadIdx.x;
    int v = (tid < NCHUNKS) ? chunk_cnt[tid] : 0;
    t[tid] = v;
    __syncthreads();
    for (int off = 1; off < 256; off <<= 1) {
        int u = 0;
        if (tid >= off) u = t[tid - off];
        __syncthreads();
        if (tid >= off) t[tid] += u;
        __syncthreads();
    }
    if (tid < NCHUNKS) csum[tid] = t[tid] - v;
}

__global__ __launch_bounds__(256) void bin_edges(const int* __restrict__ erow,
                                                 const int* __restrict__ ecol,
                                                 const float* __restrict__ eval,
                                                 const int* __restrict__ hist_all,
                                                 const int* __restrict__ csum,
                                                 uint2* __restrict__ bin) {
    __shared__ int hist[256];    // counts -> inclusive scan
    __shared__ int scnt[256];
    __shared__ int delta[256];   // run_base - excl
    __shared__ uint2 rec[BIN_TILE];
    const int tid = threadIdx.x;
    const int base = blockIdx.x * BIN_TILE;

    hist[tid] = 0;
    __syncthreads();

    int r[8]; unsigned pk[8];
#pragma unroll
    for (int j = 0; j < 8; ++j) {
        int e = base + j * 256 + tid;
        if (e < N_EDGES) {
            r[j] = erow[e];
            pk[j] = (((unsigned)ecol[e]) << 15) | (f2bf(eval[e]) & 0x7FFFu);
            atomicAdd(&hist[r[j] >> CHUNK_SHIFT], 1);
        } else {
            r[j] = -1;
        }
    }
    __syncthreads();

    const int cntb = hist[tid];
    for (int off = 1; off < 256; off <<= 1) {
        int u = 0;
        if (tid >= off) u = hist[tid - off];
        __syncthreads();
        if (tid >= off) hist[tid] += u;
        __syncthreads();
    }
    const int excl = hist[tid] - cntb;
    if (tid < NCHUNKS)
        delta[tid] = csum[tid] + hist_all[blockIdx.x * PADC + tid] - excl;
    scnt[tid] = 0;
    __syncthreads();

#pragma unroll
    for (int j = 0; j < 8; ++j) {
        if (r[j] >= 0) {
            int b = r[j] >> CHUNK_SHIFT;
            int s = (b ? hist[b - 1] : 0) + atomicAdd(&scnt[b], 1);
            rec[s] = make_uint2(pk[j], (unsigned)r[j]);
        }
    }
    __syncthreads();

    const int n = min(BIN_TILE, N_EDGES - base);
    for (int s = tid; s < n; s += 256) {
        uint2 q = rec[s];
        bin[delta[(int)q.y >> CHUNK_SHIFT] + s] = q;
    }
}

// Per chunk: LDS row histogram + scan -> row_ptr; LDS cursors -> cv scatter.
__global__ __launch_bounds__(512) void sort_chunk(const int* __restrict__ csum,
                                                  const uint2* __restrict__ bin,
                                                  int* __restrict__ row_ptr,
                                                  unsigned* __restrict__ cv) {
    __shared__ int h[CHUNK];
    const int b = blockIdx.x;
    const int tid = threadIdx.x;
    const int start = csum[b];
    const int end = (b + 1 < NCHUNKS) ? csum[b + 1] : N_EDGES;

    h[tid] = 0;
    __syncthreads();
    {
        int i = start + tid;
        for (; i + 3 * 512 < end; i += 4 * 512) {
            int r0 = (int)bin[i].y, r1 = (int)bin[i + 512].y;
            int r2 = (int)bin[i + 1024].y, r3 = (int)bin[i + 1536].y;
            atomicAdd(&h[r0 & (CHUNK - 1)], 1);
            atomicAdd(&h[r1 & (CHUNK - 1)], 1);
            atomicAdd(&h[r2 & (CHUNK - 1)], 1);
            atomicAdd(&h[r3 & (CHUNK - 1)], 1);
        }
        for (; i < end; i += 512)
            atomicAdd(&h[(int)bin[i].y & (CHUNK - 1)], 1);
    }
    __syncthreads();

    const int cnt = h[tid];
    for (int off = 1; off < 512; off <<= 1) {
        int u = 0;
        if (tid >= off) u = h[tid - off];
        __syncthreads();
        if (tid >= off) h[tid] += u;
        __syncthreads();
    }
    const int rp = start + h[tid] - cnt;        // global row start
    const int row = (b << CHUNK_SHIFT) + tid;
    if (row < N_NODES) row_ptr[row] = rp;
    if (b == NCHUNKS - 1 && tid == 0) row_ptr[N_NODES] = N_EDGES;
    h[tid] = rp;                                 // becomes the cursor
    __syncthreads();

    int i = start + tid;
    for (; i + 3 * 512 < end; i += 4 * 512) {
        uint2 q0 = bin[i], q1 = bin[i + 512], q2 = bin[i + 1024], q3 = bin[i + 1536];
        int p0 = atomicAdd(&h[(int)q0.y & (CHUNK - 1)], 1);
        int p1 = atomicAdd(&h[(int)q1.y & (CHUNK - 1)], 1);
        int p2 = atomicAdd(&h[(int)q2.y & (CHUNK - 1)], 1);
        int p3 = atomicAdd(&h[(int)q3.y & (CHUNK - 1)], 1);
        cv[p0] = q0.x; cv[p1] = q1.x; cv[p2] = q2.x; cv[p3] = q3.x;
    }
    for (; i < end; i += 512) {
        uint2 q = bin[i];
        int p = atomicAdd(&h[(int)q.y & (CHUNK - 1)], 1);
        cv[p] = q.x;
    }
}

// ---------------------------------------------------------------------------
// Aggregate: one wave per row, bf16 x gather (8 B/lane), fp32 accumulate,
// bf16 tmp write. Unroll-8 -> 8 independent 512B row gathers in flight
// (latency-bound kernel); deg from row_ptr diff (cnt array removed).
// ---------------------------------------------------------------------------
__global__ __launch_bounds__(256) void gather_rows(const int* __restrict__ row_ptr,
                                                   const unsigned* __restrict__ cv,
                                                   const unsigned short* __restrict__ xh,
                                                   unsigned short* __restrict__ tmp) {
    const int row = blockIdx.x * 4 + (threadIdx.x >> 6);
    if (row >= N_NODES) return;
    const int lane = threadIdx.x & 63;
    const int start = row_ptr[row];
    const int deg = row_ptr[row + 1] - start;
    const unsigned* __restrict__ p = cv + start;
    const uint2* __restrict__ x2 = (const uint2*)xh;   // row = 64 x uint2 (4 bf16 each)

    float a0 = 0.f, a1 = 0.f, a2 = 0.f, a3 = 0.f;
    int i = 0;
    for (; i + 7 < deg; i += 8) {
        unsigned e[8]; uint2 g[8];
#pragma unroll
        for (int j = 0; j < 8; ++j) e[j] = p[i + j];
#pragma unroll
        for (int j = 0; j < 8; ++j) g[j] = x2[(size_t)(e[j] >> 15) * 64 + lane];
#pragma unroll
        for (int j = 0; j < 8; ++j) {
            float v = __uint_as_float((e[j] & 0x7FFFu) << 16);
            a0 = fmaf(v, __uint_as_float(g[j].x << 16), a0);
            a1 = fmaf(v, __uint_as_float(g[j].x & 0xFFFF0000u), a1);
            a2 = fmaf(v, __uint_as_float(g[j].y << 16), a2);
            a3 = fmaf(v, __uint_as_float(g[j].y & 0xFFFF0000u), a3);
        }
    }
    for (; i + 3 < deg; i += 4) {
        unsigned e[4]; uint2 g[4];
#pragma unroll
        for (int j = 0; j < 4; ++j) e[j] = p[i + j];
#pragma unroll
        for (int j = 0; j < 4; ++j) g[j] = x2[(size_t)(e[j] >> 15) * 64 + lane];
#pragma unroll
        for (int j = 0; j < 4; ++j) {
            float v = __uint_as_float((e[j] & 0x7FFFu) << 16);
            a0 = fmaf(v, __uint_as_float(g[j].x << 16), a0);
            a1 = fmaf(v, __uint_as_float(g[j].x & 0xFFFF0000u), a1);
            a2 = fmaf(v, __uint_as_float(g[j].y << 16), a2);
            a3 = fmaf(v, __uint_as_float(g[j].y & 0xFFFF0000u), a3);
        }
    }
    for (; i < deg; ++i) {
        unsigned e0 = p[i];
        uint2 g0 = x2[(size_t)(e0 >> 15) * 64 + lane];
        float v0 = __uint_as_float((e0 & 0x7FFFu) << 16);
        a0 = fmaf(v0, __uint_as_float(g0.x << 16), a0);
        a1 = fmaf(v0, __uint_as_float(g0.x & 0xFFFF0000u), a1);
        a2 = fmaf(v0, __uint_as_float(g0.y << 16), a2);
        a3 = fmaf(v0, __uint_as_float(g0.y & 0xFFFF0000u), a3);
    }
    ushort4 o = make_ushort4(f2bf(a0), f2bf(a1), f2bf(a2), f2bf(a3));
    *(ushort4*)&tmp[(size_t)row * 256 + lane * 4] = o;
}

// ---------------------------------------------------------------------------
// out = relu(tmp @ W + bias) via bf16 MFMA 16x16x32.
// 64x256 block (grid.y gone): A read ONCE (51.2 MB, was 102.4), B (128KB)
// L2-resident. 4 waves split N; wave tile 64x64 = 4x4 tiles of 16x16.
// LDS 46KB -> 3 blocks/CU.
// ---------------------------------------------------------------------------
#define GBM 64
#define GBK 64
#define LDK 72

__global__ __launch_bounds__(256) void gemm_mfma(
    const unsigned short* __restrict__ A,    // tmp bf16 [M][256]
    const unsigned short* __restrict__ Bt,   // Wt bf16 [N][K] = [256][256]
    const float* __restrict__ bias,
    float* __restrict__ C, int M)
{
    __shared__ unsigned short As[GBM * LDK];
    __shared__ unsigned short Bs[UNITS * LDK];

    const int tid = threadIdx.x;
    const int lane = tid & 63;
    const int wave_n = tid >> 6;            // 0..3, n-split only
    const int block_m = blockIdx.x * GBM;

    const int quad = lane >> 4;
    const int l16 = lane & 15;

    const int ar = tid >> 2;                // A staging: row 0..63
    const int aseg = tid & 3;               // 16-short segment

    f32x4 acc[4][4];
#pragma unroll
    for (int i = 0; i < 4; ++i)
#pragma unroll
        for (int j = 0; j < 4; ++j)
            acc[i][j] = {0.f, 0.f, 0.f, 0.f};

    for (int k0 = 0; k0 < DFEAT; k0 += GBK) {
        // --- stage A tile 64x64 (guarded): 32B/thread ---
        {
            const int gm = block_m + ar;
            uint4 v0 = {}, v1 = {};
            if (gm < M) {
                const uint4* src = (const uint4*)(A + (size_t)gm * DFEAT + k0 + aseg * 16);
                v0 = src[0]; v1 = src[1];
            }
            uint4* dst = (uint4*)&As[ar * LDK + aseg * 16];
            dst[0] = v0; dst[1] = v1;
        }
        // --- stage B tile 256x64: one full row-segment (128B) per thread ---
        {
            const uint4* src = (const uint4*)(Bt + (size_t)tid * DFEAT + k0);
            uint4* dst = (uint4*)&Bs[tid * LDK];
            uint4 v0 = src[0], v1 = src[1], v2 = src[2], v3 = src[3];
            uint4 v4 = src[4], v5 = src[5], v6 = src[6], v7 = src[7];
            dst[0] = v0; dst[1] = v1; dst[2] = v2; dst[3] = v3;
            dst[4] = v4; dst[5] = v5; dst[6] = v6; dst[7] = v7;
        }
        __syncthreads();

#pragma unroll
        for (int kc = 0; kc < 2; ++kc) {
            const int ko = kc * 32 + quad * 8;
            bf16x8 af[4], bfr[4];
#pragma unroll
            for (int i = 0; i < 4; ++i)
                af[i] = *(const bf16x8*)&As[(i * 16 + l16) * LDK + ko];
#pragma unroll
            for (int j = 0; j < 4; ++j)
                bfr[j] = *(const bf16x8*)&Bs[(wave_n * 64 + j * 16 + l16) * LDK + ko];
#pragma unroll
            for (int i = 0; i < 4; ++i)
#pragma unroll
                for (int j = 0; j < 4; ++j)
                    acc[i][j] = __builtin_amdgcn_mfma_f32_16x16x32_bf16(
                        af[i], bfr[j], acc[i][j], 0, 0, 0);
        }
        __syncthreads();
    }

    // epilogue: bias + relu
#pragma unroll
    for (int j = 0; j < 4; ++j) {
        const int n = wave_n * 64 + j * 16 + l16;
        const float bj = bias[n];
#pragma unroll
        for (int i = 0; i < 4; ++i) {
            const int m0 = block_m + i * 16 + quad * 4;
#pragma unroll
            for (int rg = 0; rg < 4; ++rg) {
                const int m = m0 + rg;
                if (m < M)
                    C[(size_t)m * UNITS + n] = fmaxf(acc[i][j][rg] + bj, 0.f);
            }
        }
    }
}

extern "C" void kernel_launch(void* const* d_in, const int* in_sizes, int n_in,
                              void* d_out, int out_size, void* d_ws, size_t ws_size,
                              hipStream_t stream) {
    const int*   erow = (const int*)d_in[0];
    const int*   ecol = (const int*)d_in[1];
    const float* eval = (const float*)d_in[2];
    const float* x    = (const float*)d_in[3];
    const float* w    = (const float*)d_in[4];
    const float* bias = (const float*)d_in[5];
    float* out = (float*)d_out;

    // Workspace carve-up (bytes, all 16B-aligned):
    //   tmp bf16   : 51,200,000
    //   row_ptr    : 400,016   (N_NODES+1 ints)
    //   csum       : 1,024
    //   chunk_cnt  : 1,024
    //   cv (u32)   : 12,800,000
    //   Wt bf16    : 131,072
    //   bin (u64)  : 25,600,000
    //   hist_all   : 1,300,416  (1563 x 208 ints)   total ~91.4 MB
    char* ws = (char*)d_ws;
    unsigned short* tmp       = (unsigned short*)(ws);
    int*            row_ptr   = (int*)(ws + 51200000);
    int*            csum      = (int*)(ws + 51600016);
    int*            chunk_cnt = (int*)(ws + 51601040);
    unsigned*       cv        = (unsigned*)(ws + 51602064);
    unsigned short* wt        = (unsigned short*)(ws + 64402064);
    uint2*          bin       = (uint2*)(ws + 64533136);
    int*            hist_all  = (int*)(ws + 90133136);

    // xh (bf16 x, 51.2 MB) lives in d_out's buffer — dead before gemm writes out.
    unsigned short* xh = (unsigned short*)d_out;

    convert_x<<<(N_NODES * DFEAT / 4) / 256, 256, 0, stream>>>((const float4*)x, xh);
    convert_w<<<UNITS, DFEAT, 0, stream>>>(w, wt);

    // CSR build — zero global atomics
    chunk_hist<<<BIN_NWG, 256, 0, stream>>>(erow, hist_all);
    col_scan<<<NCHUNKS, 256, 0, stream>>>(hist_all, chunk_cnt);
    scan_chunks<<<1, 256, 0, stream>>>(chunk_cnt, csum);
    bin_edges<<<BIN_NWG, 256, 0, stream>>>(erow, ecol, eval, hist_all, csum, bin);
    sort_chunk<<<NCHUNKS, 512, 0, stream>>>(csum, bin, row_ptr, cv);

    // tmp = A_coo @ X (bf16 in / fp32 acc / bf16 out)
    gather_rows<<<(N_NODES + 3) / 4, 256, 0, stream>>>(row_ptr, cv, xh, tmp);

    // out = relu(tmp @ W + bias) via bf16 MFMA
    gemm_mfma<<<(N_NODES + GBM - 1) / GBM, 256, 0, stream>>>(tmp, wt, bias, out, N_NODES);
}